// Round 1
// baseline (1299.807 us; speedup 1.0000x reference)
//
#include <hip/hip_runtime.h>
#include <stdint.h>

typedef __bf16 bf16_t;
typedef __bf16 bf16x8 __attribute__((ext_vector_type(8)));
typedef float f32x4 __attribute__((ext_vector_type(4)));

#define MFMA16(a, b, c) __builtin_amdgcn_mfma_f32_16x16x32_bf16(a, b, c, 0, 0, 0)

__device__ __forceinline__ void gload_lds16(const bf16_t* g, bf16_t* l) {
  __builtin_amdgcn_global_load_lds(
      (const __attribute__((address_space(1))) void*)g,
      (__attribute__((address_space(3))) void*)l, 16, 0, 0);
}

// ---------------------------------------------------------------------------
// Convert x fp32 -> bf16, 8 elements/thread
__global__ __launch_bounds__(256) void cvt_x_k(const float* __restrict__ x,
                                               bf16_t* __restrict__ xb, int n8) {
  int i = blockIdx.x * 256 + threadIdx.x;
  if (i >= n8) return;
  const float4* xp = (const float4*)x + (size_t)i * 2;
  float4 f0 = xp[0], f1 = xp[1];
  bf16x8 o = {(bf16_t)f0.x, (bf16_t)f0.y, (bf16_t)f0.z, (bf16_t)f0.w,
              (bf16_t)f1.x, (bf16_t)f1.y, (bf16_t)f1.z, (bf16_t)f1.w};
  *(bf16x8*)(xb + (size_t)i * 8) = o;
}

// Transpose+convert weight [256, N] fp32 -> [N, 256] bf16. grid = N blocks.
__global__ __launch_bounds__(256) void cvt_wT_k(const float* __restrict__ w,
                                                bf16_t* __restrict__ wT, int N) {
  int n = blockIdx.x, k = threadIdx.x;
  wT[(size_t)n * 256 + k] = (bf16_t)w[(size_t)k * N + n];
}

// ---------------------------------------------------------------------------
// GEMM: C[M, ncols-slice] = A[M,256] @ B  with BT[n][k] pre-transposed bf16.
// Block tile 128x128, BK=64, 4 waves in 2x2, each wave 4x4 16x16 MFMA tiles.
// XOR-swizzled LDS (chunk c at phys c^(row&7)) -> conflict-free ds_read_b128
// while keeping global_load_lds's lane-contiguous destination constraint.
__global__ __launch_bounds__(256) void gemm256(const bf16_t* __restrict__ A,
                                               const bf16_t* __restrict__ BT,
                                               int ncols,
                                               bf16_t* __restrict__ outb,
                                               float* __restrict__ outf,
                                               const float* __restrict__ bias) {
  __shared__ __align__(16) bf16_t sA[128 * 64];
  __shared__ __align__(16) bf16_t sB[128 * 64];
  const int tid = threadIdx.x;
  const int lane = tid & 63, wave = tid >> 6;
  const int lm = lane & 15, quad = lane >> 4;
  const int mBase = blockIdx.y * 128;
  const int nBase = blockIdx.x * 128;
  const int wm = (wave >> 1) * 64, wn = (wave & 1) * 64;

  f32x4 acc[4][4];
#pragma unroll
  for (int i = 0; i < 4; i++)
#pragma unroll
    for (int j = 0; j < 4; j++) acc[i][j] = {0.f, 0.f, 0.f, 0.f};

  const bf16_t* Ab = A + (size_t)mBase * 256;
  const bf16_t* Bb = BT + (size_t)nBase * 256;

  for (int kb = 0; kb < 4; ++kb) {
    const int k0 = kb * 64;
#pragma unroll
    for (int it = 0; it < 4; ++it) {
      int cid = it * 256 + wave * 64 + lane;
      int row = cid >> 3, kcp = cid & 7;
      int kcl = kcp ^ (row & 7);
      bf16_t* dstA = sA + (it * 256 + wave * 64) * 8;  // wave-uniform base
      bf16_t* dstB = sB + (it * 256 + wave * 64) * 8;
      gload_lds16(Ab + (size_t)row * 256 + k0 + kcl * 8, dstA);
      gload_lds16(Bb + (size_t)row * 256 + k0 + kcl * 8, dstB);
    }
    __syncthreads();
#pragma unroll
    for (int kk = 0; kk < 64; kk += 32) {
      int c = (kk >> 3) + quad;
      bf16x8 af[4], bfr[4];
#pragma unroll
      for (int mt = 0; mt < 4; mt++) {
        int m = wm + mt * 16 + lm;
        af[mt] = *(const bf16x8*)(sA + m * 64 + ((c ^ (m & 7)) << 3));
      }
#pragma unroll
      for (int nt = 0; nt < 4; nt++) {
        int n = wn + nt * 16 + lm;
        bfr[nt] = *(const bf16x8*)(sB + n * 64 + ((c ^ (n & 7)) << 3));
      }
#pragma unroll
      for (int mt = 0; mt < 4; mt++)
#pragma unroll
        for (int nt = 0; nt < 4; nt++)
          acc[mt][nt] = MFMA16(af[mt], bfr[nt], acc[mt][nt]);
    }
    __syncthreads();
  }

  if (outb) {
#pragma unroll
    for (int mt = 0; mt < 4; mt++)
#pragma unroll
      for (int nt = 0; nt < 4; nt++) {
        int col = nBase + wn + nt * 16 + lm;
        int rbase = mBase + wm + mt * 16 + quad * 4;
#pragma unroll
        for (int r = 0; r < 4; r++)
          outb[(size_t)(rbase + r) * ncols + col] = (bf16_t)acc[mt][nt][r];
      }
  } else {
#pragma unroll
    for (int mt = 0; mt < 4; mt++)
#pragma unroll
      for (int nt = 0; nt < 4; nt++) {
        int col = nBase + wn + nt * 16 + lm;
        float bv = bias[col];
        int rbase = mBase + wm + mt * 16 + quad * 4;
#pragma unroll
        for (int r = 0; r < 4; r++)
          outf[(size_t)(rbase + r) * ncols + col] = acc[mt][nt][r] + bv;
      }
  }
}

// ---------------------------------------------------------------------------
// Fused window attention. One block (256 thr, 4 waves) per (b, h).
// N=98 padded to 112; PV K padded to 128. S fp32 row-stride 116 (464B, 16B
// aligned); P bf16 aliased in-place per row (write byte 2j after read 4j).
// LDS total 80640B -> 2 blocks/CU.
__global__ __launch_bounds__(256) void attn_win(const bf16_t* __restrict__ qkv,
                                                const float* __restrict__ mask,
                                                const float* __restrict__ btab,
                                                bf16_t* __restrict__ y) {
  __shared__ __align__(16) bf16_t sQ[112 * 40];
  __shared__ __align__(16) bf16_t sK[112 * 40];
  __shared__ __align__(16) bf16_t sVT[32 * 136];
  __shared__ __align__(16) float sS[112 * 116];
  __shared__ float sTab[512];
  __shared__ float sInv[112];

  const int tid = threadIdx.x;
  const int h = blockIdx.x, b = blockIdx.y;
  const int lane = tid & 63, wave = tid >> 6;
  const int lm = lane & 15, quad = lane >> 4;

  // zero VT (pad cols j>=98 must be 0, not NaN-garbage, since P pad is 0)
  for (int i = tid; i < 32 * 136 / 2; i += 256) ((uint32_t*)sVT)[i] = 0;
  for (int i = tid; i < 507; i += 256) sTab[i] = btab[i * 8 + h];
  __syncthreads();

  // stage q, k, v^T
  const bf16_t* qb = qkv + (size_t)b * 98 * 768 + h * 32;
  for (int idx = tid; idx < 98 * 4; idx += 256) {
    int r = idx >> 2, c = (idx & 3) << 3;
    const bf16_t* g = qb + (size_t)r * 768 + c;
    *(uint4*)(sQ + r * 40 + c) = *(const uint4*)(g);
    *(uint4*)(sK + r * 40 + c) = *(const uint4*)(g + 256);
    uint4 vv = *(const uint4*)(g + 512);
    const bf16_t* vp = (const bf16_t*)&vv;
#pragma unroll
    for (int i2 = 0; i2 < 8; i2++) sVT[(c + i2) * 136 + r] = vp[i2];
  }
  __syncthreads();

  // S = scale * Q K^T + bias + mask
  const float* mp = mask + (size_t)(b & 63) * 98 * 98;
  const float scale = 0.17677669529663687f;
  for (int t = wave; t < 49; t += 4) {
    int m0 = (t / 7) * 16, n0 = (t % 7) * 16;
    bf16x8 aq = *(const bf16x8*)(sQ + (m0 + lm) * 40 + quad * 8);
    bf16x8 bk = *(const bf16x8*)(sK + (n0 + lm) * 40 + quad * 8);
    f32x4 s4 = {0.f, 0.f, 0.f, 0.f};
    s4 = MFMA16(aq, bk, s4);
    int j = n0 + lm;
    if (j < 98) {
      int dj = j / 49, rj = j - dj * 49;
      int hj = rj / 7, wj = rj - hj * 7;
#pragma unroll
      for (int r = 0; r < 4; r++) {
        int i = m0 + quad * 4 + r;
        if (i < 98) {
          int di = i / 49, ri = i - di * 49;
          int hi = ri / 7, wi = ri - hi * 7;
          int bidx = (di - dj + 1) * 169 + (hi - hj + 6) * 13 + (wi - wj + 6);
          sS[i * 116 + j] = s4[r] * scale + sTab[bidx] + mp[i * 98 + j];
        }
      }
    }
  }
  __syncthreads();

  // softmax (1 thread/row); P = exp(S - max) stored bf16 in-place; 1/sum kept
  if (tid < 98) {
    int i = tid;
    float* Srow = sS + i * 116;
    // pass 1: max (rotated start to break 8-way bank aliasing; read-only)
    float mx = -1e30f;
    int jj = tid;
    for (int cnt = 0; cnt < 98; cnt++) {
      mx = fmaxf(mx, Srow[jj]);
      jj++;
      if (jj == 98) jj = 0;
    }
    // pass 2: sequential (in-place alias safe: write 2j after read 4j)
    bf16_t* Prow = (bf16_t*)Srow;
    float sum = 0.f;
    for (int j = 0; j < 98; j++) {
      float e = __expf(Srow[j] - mx);
      sum += e;
      Prow[j] = (bf16_t)e;
    }
#pragma unroll
    for (int j = 98; j < 128; j++) Prow[j] = (bf16_t)0.f;
    sInv[i] = 1.f / sum;
  }
  __syncthreads();

  // O = (P V) * inv_sum  -> y[b, n, h*32+d] bf16
  bf16_t* yb = y + (size_t)b * 98 * 256 + h * 32;
  for (int t = wave; t < 14; t += 4) {
    int m0 = (t >> 1) * 16, n0 = (t & 1) * 16;
    f32x4 o4 = {0.f, 0.f, 0.f, 0.f};
#pragma unroll
    for (int k0 = 0; k0 < 128; k0 += 32) {
      bf16x8 ap = *(const bf16x8*)((const bf16_t*)((const char*)sS +
                                                   (size_t)(m0 + lm) * 464) +
                                   k0 + quad * 8);
      bf16x8 bv = *(const bf16x8*)(sVT + (n0 + lm) * 136 + k0 + quad * 8);
      o4 = MFMA16(ap, bv, o4);
    }
    int d = n0 + lm;
#pragma unroll
    for (int r = 0; r < 4; r++) {
      int i = m0 + quad * 4 + r;
      if (i < 98) yb[(size_t)i * 256 + d] = (bf16_t)(o4[r] * sInv[i]);
    }
  }
}

// ---------------------------------------------------------------------------
extern "C" void kernel_launch(void* const* d_in, const int* in_sizes, int n_in,
                              void* d_out, int out_size, void* d_ws,
                              size_t ws_size, hipStream_t stream) {
  const float* x = (const float*)d_in[0];       // [2048, 98, 256]
  const float* mask = (const float*)d_in[1];    // [64, 98, 98]
  const float* qkv_w = (const float*)d_in[2];   // [256, 768]
  const float* proj_w = (const float*)d_in[3];  // [256, 256]
  const float* proj_b = (const float*)d_in[4];  // [256]
  const float* btab = (const float*)d_in[5];    // [507, 8]
  float* out = (float*)d_out;                   // [2048, 98, 256]

  char* ws = (char*)d_ws;
  // ws layout (bytes):
  //   qkv bf16 [200704, 768]           : 308,281,344
  //   y/xb bf16 [200704, 256] (aliased): 102,760,448  (xb dead before y write)
  //   wT bf16 [768, 256]               : 393,216
  //   pT bf16 [256, 256]               : 131,072     total ~392.5 MiB
  bf16_t* qkv = (bf16_t*)ws;
  bf16_t* ybuf = (bf16_t*)(ws + 308281344);
  bf16_t* xb = ybuf;  // alias: consumed by gemm1 before attn writes y
  bf16_t* wT = (bf16_t*)(ws + 308281344 + 102760448);
  bf16_t* pT = (bf16_t*)(ws + 308281344 + 102760448 + 393216);

  // 1) converts
  cvt_x_k<<<25088, 256, 0, stream>>>(x, xb, 6422528);  // 51,380,224 / 8
  cvt_wT_k<<<768, 256, 0, stream>>>(qkv_w, wT, 768);
  cvt_wT_k<<<256, 256, 0, stream>>>(proj_w, pT, 256);

  // 2) qkv = x @ qkv_w   (M=200704, K=256, N=768)
  gemm256<<<dim3(6, 1568), 256, 0, stream>>>(xb, wT, 768, qkv, nullptr,
                                             nullptr);

  // 3) fused window attention -> y
  attn_win<<<dim3(8, 2048), 256, 0, stream>>>(qkv, mask, btab, ybuf);

  // 4) out = y @ proj_w + proj_b  (M=200704, K=256, N=256)
  gemm256<<<dim3(2, 1568), 256, 0, stream>>>(ybuf, pT, 256, nullptr, out,
                                             proj_b);
}

// Round 2
// 803.363 us; speedup vs baseline: 1.6180x; 1.6180x over previous
//
#include <hip/hip_runtime.h>
#include <stdint.h>

typedef __bf16 bf16_t;
typedef __bf16 bf16x8 __attribute__((ext_vector_type(8)));
typedef float f32x4 __attribute__((ext_vector_type(4)));

#define MFMA16(a, b, c) __builtin_amdgcn_mfma_f32_16x16x32_bf16(a, b, c, 0, 0, 0)

__device__ __forceinline__ void gload_lds16(const bf16_t* g, bf16_t* l) {
  __builtin_amdgcn_global_load_lds(
      (const __attribute__((address_space(1))) void*)g,
      (__attribute__((address_space(3))) void*)l, 16, 0, 0);
}

__device__ __forceinline__ int sw4(int i) {  // nibble swap of 0..15
  return ((i & 3) << 2) | ((i >> 2) & 3);
}

// ---------------------------------------------------------------------------
// Convert x fp32 -> bf16, 8 elements/thread
__global__ __launch_bounds__(256) void cvt_x_k(const float* __restrict__ x,
                                               bf16_t* __restrict__ xb, int n8) {
  int i = blockIdx.x * 256 + threadIdx.x;
  if (i >= n8) return;
  const float4* xp = (const float4*)x + (size_t)i * 2;
  float4 f0 = xp[0], f1 = xp[1];
  bf16x8 o = {(bf16_t)f0.x, (bf16_t)f0.y, (bf16_t)f0.z, (bf16_t)f0.w,
              (bf16_t)f1.x, (bf16_t)f1.y, (bf16_t)f1.z, (bf16_t)f1.w};
  *(bf16x8*)(xb + (size_t)i * 8) = o;
}

// Transpose+convert weight [256, N] fp32 -> [N, 256] bf16. grid = N blocks.
__global__ __launch_bounds__(256) void cvt_wT_k(const float* __restrict__ w,
                                                bf16_t* __restrict__ wT, int N) {
  int n = blockIdx.x, k = threadIdx.x;
  wT[(size_t)n * 256 + k] = (bf16_t)w[(size_t)k * N + n];
}

// ---------------------------------------------------------------------------
// GEMM: C[M, ncols-slice] = A[M,256] @ B  with BT[n][k] pre-transposed bf16.
__global__ __launch_bounds__(256) void gemm256(const bf16_t* __restrict__ A,
                                               const bf16_t* __restrict__ BT,
                                               int ncols,
                                               bf16_t* __restrict__ outb,
                                               float* __restrict__ outf,
                                               const float* __restrict__ bias) {
  __shared__ __align__(16) bf16_t sA[128 * 64];
  __shared__ __align__(16) bf16_t sB[128 * 64];
  const int tid = threadIdx.x;
  const int lane = tid & 63, wave = tid >> 6;
  const int lm = lane & 15, quad = lane >> 4;
  const int mBase = blockIdx.y * 128;
  const int nBase = blockIdx.x * 128;
  const int wm = (wave >> 1) * 64, wn = (wave & 1) * 64;

  f32x4 acc[4][4];
#pragma unroll
  for (int i = 0; i < 4; i++)
#pragma unroll
    for (int j = 0; j < 4; j++) acc[i][j] = {0.f, 0.f, 0.f, 0.f};

  const bf16_t* Ab = A + (size_t)mBase * 256;
  const bf16_t* Bb = BT + (size_t)nBase * 256;

  for (int kb = 0; kb < 4; ++kb) {
    const int k0 = kb * 64;
#pragma unroll
    for (int it = 0; it < 4; ++it) {
      int cid = it * 256 + wave * 64 + lane;
      int row = cid >> 3, kcp = cid & 7;
      int kcl = kcp ^ (row & 7);
      bf16_t* dstA = sA + (it * 256 + wave * 64) * 8;  // wave-uniform base
      bf16_t* dstB = sB + (it * 256 + wave * 64) * 8;
      gload_lds16(Ab + (size_t)row * 256 + k0 + kcl * 8, dstA);
      gload_lds16(Bb + (size_t)row * 256 + k0 + kcl * 8, dstB);
    }
    __syncthreads();
#pragma unroll
    for (int kk = 0; kk < 64; kk += 32) {
      int c = (kk >> 3) + quad;
      bf16x8 af[4], bfr[4];
#pragma unroll
      for (int mt = 0; mt < 4; mt++) {
        int m = wm + mt * 16 + lm;
        af[mt] = *(const bf16x8*)(sA + m * 64 + ((c ^ (m & 7)) << 3));
      }
#pragma unroll
      for (int nt = 0; nt < 4; nt++) {
        int n = wn + nt * 16 + lm;
        bfr[nt] = *(const bf16x8*)(sB + n * 64 + ((c ^ (n & 7)) << 3));
      }
#pragma unroll
      for (int mt = 0; mt < 4; mt++)
#pragma unroll
        for (int nt = 0; nt < 4; nt++)
          acc[mt][nt] = MFMA16(af[mt], bfr[nt], acc[mt][nt]);
    }
    __syncthreads();
  }

  if (outb) {
#pragma unroll
    for (int mt = 0; mt < 4; mt++)
#pragma unroll
      for (int nt = 0; nt < 4; nt++) {
        int col = nBase + wn + nt * 16 + lm;
        int rbase = mBase + wm + mt * 16 + quad * 4;
#pragma unroll
        for (int r = 0; r < 4; r++)
          outb[(size_t)(rbase + r) * ncols + col] = (bf16_t)acc[mt][nt][r];
      }
  } else {
#pragma unroll
    for (int mt = 0; mt < 4; mt++)
#pragma unroll
      for (int nt = 0; nt < 4; nt++) {
        int col = nBase + wn + nt * 16 + lm;
        float bv = bias[col];
        int rbase = mBase + wm + mt * 16 + quad * 4;
#pragma unroll
        for (int r = 0; r < 4; r++)
          outf[(size_t)(rbase + r) * ncols + col] = acc[mt][nt][r] + bv;
      }
  }
}

// ---------------------------------------------------------------------------
// Fused window attention, v2: register-resident S, wave-parallel softmax.
// One block (4 waves) per (b,h). Wave w owns S row-tiles {w, w+4} of 7.
// S kept in VGPRs (C-layout); per-row max/sum via shfl_xor over the 16-lane
// lm-group. P round-trips through LDS (bf16) only for C->A layout transform,
// with nibble-swap XOR swizzle (conflict-free for column-wise P stores, VT
// transpose writes, and b128 fragment reads). LDS 39.4KB -> 4 blocks/CU.
__global__ __launch_bounds__(256, 4) void attn_win(
    const bf16_t* __restrict__ qkv, const float* __restrict__ mask,
    const float* __restrict__ btab, bf16_t* __restrict__ y) {
  __shared__ __align__(16) bf16_t sP[112 * 128];
  __shared__ __align__(16) bf16_t sVT[32 * 128];
  __shared__ float sTab[512];
  __shared__ int sU[112];

  const int tid = threadIdx.x;
  const int h = blockIdx.x, b = blockIdx.y;
  const int lane = tid & 63, wave = tid >> 6;
  const int lm = lane & 15, quad = lane >> 4;

  // ---- phase A: zero P (for K-pad cols 112..127), bias table, u[], VT ----
  {
    uint4 z = {0, 0, 0, 0};
    uint4* p = (uint4*)sP;
    for (int i = tid; i < 112 * 128 / 8; i += 256) p[i] = z;
  }
  // zero VT pad cols j in [98,128) (disjoint from staged j<98: no race)
  for (int idx = tid; idx < 1024; idx += 256) {
    int d = idx >> 5, j = 96 + (idx & 31);
    if (j >= 98)
      sVT[d * 128 + (((j >> 3) ^ sw4(d & 15)) << 3) + (j & 7)] = (bf16_t)0.f;
  }
  for (int i = tid; i < 507; i += 256) sTab[i] = btab[i * 8 + h];
  if (tid < 112) {
    int n = tid;
    int d = n / 49, r = n - d * 49;
    int hh = r / 7, w = r - hh * 7;
    sU[tid] = (n < 98) ? (d * 169 + hh * 13 + w) : 0;
  }

  const bf16_t* qb = qkv + (size_t)b * 98 * 768 + h * 32;

  // VT stage: thread (j = tid&127 < 98, hf = tid>>7) handles dc = hf, hf+2
  {
    int j = tid & 127, hf = tid >> 7;
    if (j < 98) {
#pragma unroll
      for (int t = 0; t < 2; t++) {
        int dc = hf + 2 * t;
        bf16x8 v8 = *(const bf16x8*)(qb + (size_t)j * 768 + 512 + dc * 8);
#pragma unroll
        for (int e = 0; e < 8; e++) {
          int d = dc * 8 + e;
          sVT[d * 128 + (((j >> 3) ^ sw4(d & 15)) << 3) + (j & 7)] = v8[e];
        }
      }
    }
  }
  __syncthreads();

  // ---- QK^T: wave computes row-tiles rt = wave, wave+4 ----
  bf16x8 kf[7];
#pragma unroll
  for (int ct = 0; ct < 7; ct++)
    kf[ct] =
        *(const bf16x8*)(qb + (size_t)(ct * 16 + lm) * 768 + 256 + quad * 8);

  f32x4 s4[2][7];
#pragma unroll
  for (int rti = 0; rti < 2; rti++) {
    int rt = wave + rti * 4;
    if (rt <= 6) {
      bf16x8 qf = *(const bf16x8*)(qb + (size_t)(rt * 16 + lm) * 768 + quad * 8);
#pragma unroll
      for (int ct = 0; ct < 7; ct++) {
        f32x4 z = {0.f, 0.f, 0.f, 0.f};
        s4[rti][ct] = MFMA16(qf, kf[ct], z);
      }
    }
  }

  // ---- epilogue (scale+bias+mask), softmax, P store ----
  const float* mp = mask + (size_t)(b & 63) * 9604;
  const float scale = 0.17677669529663687f;
  float inv[2][4];

#pragma unroll
  for (int rti = 0; rti < 2; rti++) {
    int rt = wave + rti * 4;
    if (rt > 6) continue;
    int ib = rt * 16 + quad * 4;
    int ui[4], rb[4];
#pragma unroll
    for (int r = 0; r < 4; r++) {
      int i = ib + r;
      ui[r] = sU[i] + 253;
      rb[r] = (i < 98 ? i : 97) * 98;
    }
#pragma unroll
    for (int ct = 0; ct < 7; ct++) {
      int j = ct * 16 + lm;
      int uj = sU[j];
      int jc = j < 98 ? j : 97;
      bool jv = j < 98;
#pragma unroll
      for (int r = 0; r < 4; r++) {
        float v = s4[rti][ct][r] * scale + sTab[ui[r] - uj] + mp[rb[r] + jc];
        s4[rti][ct][r] = jv ? v : -1e30f;
      }
    }
#pragma unroll
    for (int r = 0; r < 4; r++) {
      float mx = s4[rti][0][r];
#pragma unroll
      for (int ct = 1; ct < 7; ct++) mx = fmaxf(mx, s4[rti][ct][r]);
#pragma unroll
      for (int o = 1; o < 16; o <<= 1) mx = fmaxf(mx, __shfl_xor(mx, o));
      float sum = 0.f;
#pragma unroll
      for (int ct = 0; ct < 7; ct++) {
        float e = __expf(s4[rti][ct][r] - mx);
        s4[rti][ct][r] = e;
        sum += e;
      }
#pragma unroll
      for (int o = 1; o < 16; o <<= 1) sum += __shfl_xor(sum, o);
      inv[rti][r] = 1.f / sum;
    }
    // store P bf16, swizzled: conflict-free column-wise stores
#pragma unroll
    for (int ct = 0; ct < 7; ct++) {
      int c2 = 2 * ct + (lm >> 3);
      int j7 = lm & 7;
#pragma unroll
      for (int r = 0; r < 4; r++) {
        int i = ib + r;
        sP[i * 128 + ((c2 ^ (4 * r + quad)) << 3) + j7] =
            (bf16_t)s4[rti][ct][r];
      }
    }
  }
  __syncthreads();

  // ---- O = P V (K padded to 128 with zero P cols), scale by 1/sum ----
  bf16x8 vf[2][4];
#pragma unroll
  for (int dt = 0; dt < 2; dt++)
#pragma unroll
    for (int kk = 0; kk < 4; kk++) {
      int d = dt * 16 + lm;
      vf[dt][kk] =
          *(const bf16x8*)(sVT + d * 128 + (((4 * kk + quad) ^ sw4(lm)) << 3));
    }
  bf16_t* yb = y + (size_t)b * 98 * 256 + h * 32;
#pragma unroll
  for (int rti = 0; rti < 2; rti++) {
    int rt = wave + rti * 4;
    if (rt > 6) continue;
    bf16x8 af[4];
#pragma unroll
    for (int kk = 0; kk < 4; kk++) {
      int i = rt * 16 + lm;
      af[kk] =
          *(const bf16x8*)(sP + i * 128 + (((4 * kk + quad) ^ sw4(lm)) << 3));
    }
#pragma unroll
    for (int dt = 0; dt < 2; dt++) {
      f32x4 o = {0.f, 0.f, 0.f, 0.f};
#pragma unroll
      for (int kk = 0; kk < 4; kk++) o = MFMA16(af[kk], vf[dt][kk], o);
#pragma unroll
      for (int r = 0; r < 4; r++) {
        int i = rt * 16 + quad * 4 + r;
        if (i < 98)
          yb[(size_t)i * 256 + dt * 16 + lm] = (bf16_t)(o[r] * inv[rti][r]);
      }
    }
  }
}

// ---------------------------------------------------------------------------
extern "C" void kernel_launch(void* const* d_in, const int* in_sizes, int n_in,
                              void* d_out, int out_size, void* d_ws,
                              size_t ws_size, hipStream_t stream) {
  const float* x = (const float*)d_in[0];       // [2048, 98, 256]
  const float* mask = (const float*)d_in[1];    // [64, 98, 98]
  const float* qkv_w = (const float*)d_in[2];   // [256, 768]
  const float* proj_w = (const float*)d_in[3];  // [256, 256]
  const float* proj_b = (const float*)d_in[4];  // [256]
  const float* btab = (const float*)d_in[5];    // [507, 8]
  float* out = (float*)d_out;                   // [2048, 98, 256]

  char* ws = (char*)d_ws;
  bf16_t* qkv = (bf16_t*)ws;
  bf16_t* ybuf = (bf16_t*)(ws + 308281344);
  bf16_t* xb = ybuf;  // alias: consumed by gemm1 before attn writes y
  bf16_t* wT = (bf16_t*)(ws + 308281344 + 102760448);
  bf16_t* pT = (bf16_t*)(ws + 308281344 + 102760448 + 393216);

  cvt_x_k<<<25088, 256, 0, stream>>>(x, xb, 6422528);
  cvt_wT_k<<<768, 256, 0, stream>>>(qkv_w, wT, 768);
  cvt_wT_k<<<256, 256, 0, stream>>>(proj_w, pT, 256);

  gemm256<<<dim3(6, 1568), 256, 0, stream>>>(xb, wT, 768, qkv, nullptr,
                                             nullptr);

  attn_win<<<dim3(8, 2048), 256, 0, stream>>>(qkv, mask, btab, ybuf);

  gemm256<<<dim3(2, 1568), 256, 0, stream>>>(ybuf, pT, 256, nullptr, out,
                                             proj_b);
}